// Round 1
// baseline (459.735 us; speedup 1.0000x reference)
//
#include <hip/hip_runtime.h>
#include <stdint.h>
#include <math.h>

typedef __attribute__((ext_vector_type(8))) __bf16 bf16x8;
typedef __attribute__((ext_vector_type(4))) __bf16 bf16x4;
typedef __attribute__((ext_vector_type(4))) float f32x4;

#define MFMA16(A, B, C) __builtin_amdgcn_mfma_f32_16x16x32_bf16((A), (B), (C), 0, 0, 0)

static constexpr int kT  = 2048;
static constexpr int kBA = 4;
static constexpr int kC  = 1024;
static constexpr int kH  = 16;
static constexpr int kHD = 64;

__device__ __forceinline__ void g2l16(const void* g, void* l) {
  __builtin_amdgcn_global_load_lds(
      (const __attribute__((address_space(1))) uint32_t*)g,
      (__attribute__((address_space(3))) uint32_t*)l, 16, 0, 0);
}

// ---------------- x (f32) -> bf16, row-major [M, C] ----------------
__global__ __launch_bounds__(256) void k_convert_x(const float* __restrict__ x,
                                                   __bf16* __restrict__ xb) {
  int i = (blockIdx.x * 256 + threadIdx.x) * 4;
  f32x4 v = *(const f32x4*)(x + i);
  bf16x4 o;
  o[0] = (__bf16)v[0]; o[1] = (__bf16)v[1]; o[2] = (__bf16)v[2]; o[3] = (__bf16)v[3];
  *(bf16x4*)(xb + i) = o;
}

// ---- W [K=1024, N] f32 -> W^T [N, 1024] bf16 (B^T form for GEMM) ----
__global__ __launch_bounds__(256) void k_transpose_w(const float* __restrict__ src,
                                                     __bf16* __restrict__ dst, int N) {
  __shared__ float t[32][33];
  int k0 = blockIdx.x * 32, n0 = blockIdx.y * 32;
  int c = threadIdx.x & 31, r = threadIdx.x >> 5;
#pragma unroll
  for (int i = 0; i < 4; ++i)
    t[r + i * 8][c] = src[(size_t)(k0 + r + i * 8) * N + n0 + c];
  __syncthreads();
#pragma unroll
  for (int i = 0; i < 4; ++i)
    dst[(size_t)(n0 + r + i * 8) * 1024 + k0 + c] = (__bf16)t[c][r + i * 8];
}

// ---------------- GEMM: C[m,n] = sum_k A[m,k]*Bw[n,k] (+bias) ----------------
// m97 structure: 128x128 tile, 4 waves of 64x64, BK=64, global_load_lds width 16.
// MODE 0: QKV -> scatter into q [B,H,T,hd] (scaled 0.125), k [B,H,T,hd], v^T [B,H,hd,T]
// MODE 1: proj -> f32 out [M,1024] + bias
template <int MODE>
__global__ __launch_bounds__(256) void k_gemm(const __bf16* __restrict__ A,
                                              const __bf16* __restrict__ Bw,
                                              const float* __restrict__ bias,
                                              __bf16* __restrict__ qo,
                                              __bf16* __restrict__ ko,
                                              __bf16* __restrict__ vto,
                                              float* __restrict__ out) {
  constexpr int K = 1024;
  __shared__ __bf16 As[128 * 64];
  __shared__ __bf16 Bs[128 * 64];
  const int tid = threadIdx.x;
  const int wave = tid >> 6, lane = tid & 63;
  const int lo = lane & 15, hi = lane >> 4;
  const int wm = (wave & 1) * 64, wn = (wave >> 1) * 64;
  const int m0 = blockIdx.y * 128, n0 = blockIdx.x * 128;

  f32x4 acc[4][4] = {};

  const __bf16* ga = A + (size_t)(m0 + wave * 32 + (lane >> 3)) * K + (lane & 7) * 8;
  const __bf16* gb = Bw + (size_t)(n0 + wave * 32 + (lane >> 3)) * K + (lane & 7) * 8;
  __bf16* la = As + wave * 32 * 64;
  __bf16* lb = Bs + wave * 32 * 64;

  for (int kt = 0; kt < K; kt += 64) {
#pragma unroll
    for (int i = 0; i < 4; ++i) {
      g2l16(ga + (size_t)i * 8 * K + kt, la + i * 8 * 64);
      g2l16(gb + (size_t)i * 8 * K + kt, lb + i * 8 * 64);
    }
    __syncthreads();
#pragma unroll
    for (int kk = 0; kk < 64; kk += 32) {
      bf16x8 af[4], bfr[4];
#pragma unroll
      for (int i = 0; i < 4; ++i)
        af[i] = *(const bf16x8*)&As[(wm + i * 16 + lo) * 64 + kk + hi * 8];
#pragma unroll
      for (int j = 0; j < 4; ++j)
        bfr[j] = *(const bf16x8*)&Bs[(wn + j * 16 + lo) * 64 + kk + hi * 8];
#pragma unroll
      for (int i = 0; i < 4; ++i)
#pragma unroll
        for (int j = 0; j < 4; ++j)
          acc[i][j] = MFMA16(af[i], bfr[j], acc[i][j]);
    }
    __syncthreads();
  }

  if (MODE == 0) {
#pragma unroll
    for (int j = 0; j < 4; ++j) {
      int gn = n0 + wn + j * 16 + lo;
      float bv = bias[gn];
      int which = gn >> 10;          // 0=q 1=k 2=v
      int c = gn & 1023;
      int hh = c >> 6, d = c & 63;
#pragma unroll
      for (int i = 0; i < 4; ++i) {
        int gm = m0 + wm + i * 16 + hi * 4;
#pragma unroll
        for (int r = 0; r < 4; ++r) {
          int m = gm + r;
          int bb = m >> 11, t = m & 2047;
          float val = acc[i][j][r] + bv;
          size_t bh = (size_t)(bb * 16 + hh);
          if (which == 0)
            qo[(bh * 2048 + t) * 64 + d] = (__bf16)(val * 0.125f);
          else if (which == 1)
            ko[(bh * 2048 + t) * 64 + d] = (__bf16)val;
          else
            vto[(bh * 64 + d) * 2048 + t] = (__bf16)val;
        }
      }
    }
  } else {
#pragma unroll
    for (int j = 0; j < 4; ++j) {
      int gn = n0 + wn + j * 16 + lo;
      float bv = bias[gn];
#pragma unroll
      for (int i = 0; i < 4; ++i) {
        int gm = m0 + wm + i * 16 + hi * 4;
#pragma unroll
        for (int r = 0; r < 4; ++r)
          out[(size_t)(gm + r) * 1024 + gn] = acc[i][j][r] + bv;
      }
    }
  }
}

// ---------------- Flash attention (causal, online softmax) ----------------
// grid (T/64, B*H), 256 threads = 4 waves; wave handles 16 q-rows.
// q pre-scaled by 1/sqrt(hd). K staged [key][d], V staged transposed [d][key].
__global__ __launch_bounds__(256) void k_flash(const __bf16* __restrict__ qb,
                                               const __bf16* __restrict__ kb,
                                               const __bf16* __restrict__ vt,
                                               __bf16* __restrict__ ob) {
  __shared__ __bf16 Ks[64 * 72];
  __shared__ __bf16 Vs[64 * 72];
  __shared__ __bf16 Ps[4][16 * 72];

  const int bq = (int)gridDim.x - 1 - (int)blockIdx.x;  // big tiles dispatch first
  const int bh = blockIdx.y;
  const int b = bh >> 4, h = bh & 15;
  const int tid = threadIdx.x, wave = tid >> 6, lane = tid & 63;
  const int lo = lane & 15, hi = lane >> 4;

  const __bf16* Qp = qb + ((size_t)bh * kT + bq * 64 + wave * 16) * kHD;
  bf16x8 qf0 = *(const bf16x8*)(Qp + lo * kHD + hi * 8);
  bf16x8 qf1 = *(const bf16x8*)(Qp + lo * kHD + 32 + hi * 8);

  f32x4 acc[4] = {};
  float mrow[4] = {-INFINITY, -INFINITY, -INFINITY, -INFINITY};
  float lrow[4] = {0.f, 0.f, 0.f, 0.f};

  const __bf16* Kbase = kb + (size_t)bh * kT * kHD;
  const __bf16* Vbase = vt + (size_t)bh * kHD * kT;

  for (int it = 0; it <= bq; ++it) {
    const int kt = it * 64;
    // stage K tile [64 keys][64 d] and V^T tile [64 d][64 keys], padded rows (72)
#pragma unroll
    for (int p = 0; p < 2; ++p) {
      int ee = (p * 256 + tid) * 8;
      int r = ee >> 6, c = ee & 63;
      bf16x8 vK = *(const bf16x8*)(Kbase + (size_t)(kt + r) * kHD + c);
      *(bf16x8*)&Ks[r * 72 + c] = vK;
      bf16x8 vV = *(const bf16x8*)(Vbase + (size_t)r * kT + kt + c);
      *(bf16x8*)&Vs[r * 72 + c] = vV;
    }
    __syncthreads();

    // S[16 q][64 keys] = Q K^T
    f32x4 s[4];
#pragma unroll
    for (int j = 0; j < 4; ++j) {
      bf16x8 kf0 = *(const bf16x8*)&Ks[(j * 16 + lo) * 72 + hi * 8];
      bf16x8 kf1 = *(const bf16x8*)&Ks[(j * 16 + lo) * 72 + 32 + hi * 8];
      f32x4 z = {};
      z = MFMA16(qf0, kf0, z);
      z = MFMA16(qf1, kf1, z);
      s[j] = z;
    }

    const int q0 = bq * 64 + wave * 16 + hi * 4;
    if (it == bq) {
#pragma unroll
      for (int j = 0; j < 4; ++j)
#pragma unroll
        for (int r = 0; r < 4; ++r)
          if (kt + j * 16 + lo > q0 + r) s[j][r] = -INFINITY;
    }

    // online softmax (rows live across 16 lanes of each quad)
    float mx[4], alpha[4], rs[4];
#pragma unroll
    for (int r = 0; r < 4; ++r)
      mx[r] = fmaxf(fmaxf(s[0][r], s[1][r]), fmaxf(s[2][r], s[3][r]));
#pragma unroll
    for (int off = 1; off < 16; off <<= 1)
#pragma unroll
      for (int r = 0; r < 4; ++r) mx[r] = fmaxf(mx[r], __shfl_xor(mx[r], off, 64));
#pragma unroll
    for (int r = 0; r < 4; ++r) {
      float mn = fmaxf(mrow[r], mx[r]);
      alpha[r] = __expf(mrow[r] - mn);  // exp(-inf - finite) = 0 on first tile
      mrow[r] = mn;
    }
#pragma unroll
    for (int r = 0; r < 4; ++r) {
      float t0 = 0.f;
#pragma unroll
      for (int j = 0; j < 4; ++j) {
        float p = __expf(s[j][r] - mrow[r]);
        s[j][r] = p;
        t0 += p;
      }
      rs[r] = t0;
    }
#pragma unroll
    for (int off = 1; off < 16; off <<= 1)
#pragma unroll
      for (int r = 0; r < 4; ++r) rs[r] += __shfl_xor(rs[r], off, 64);
#pragma unroll
    for (int r = 0; r < 4; ++r) lrow[r] = lrow[r] * alpha[r] + rs[r];
#pragma unroll
    for (int jd = 0; jd < 4; ++jd)
#pragma unroll
      for (int r = 0; r < 4; ++r) acc[jd][r] *= alpha[r];

    // P: C-layout -> A-layout via LDS round trip (wave-private region)
    __bf16* Pw = &Ps[wave][0];
#pragma unroll
    for (int j = 0; j < 4; ++j)
#pragma unroll
      for (int r = 0; r < 4; ++r)
        Pw[(hi * 4 + r) * 72 + j * 16 + lo] = (__bf16)s[j][r];
    __syncthreads();

    bf16x8 pf0 = *(const bf16x8*)&Pw[lo * 72 + hi * 8];
    bf16x8 pf1 = *(const bf16x8*)&Pw[lo * 72 + 32 + hi * 8];
#pragma unroll
    for (int jd = 0; jd < 4; ++jd) {
      bf16x8 vf0 = *(const bf16x8*)&Vs[(jd * 16 + lo) * 72 + hi * 8];
      bf16x8 vf1 = *(const bf16x8*)&Vs[(jd * 16 + lo) * 72 + 32 + hi * 8];
      acc[jd] = MFMA16(pf0, vf0, acc[jd]);
      acc[jd] = MFMA16(pf1, vf1, acc[jd]);
    }
    __syncthreads();
  }

  // epilogue: O / l, write o as [B,T,C] bf16 (row m = b*T+t, col = h*64+d)
  float inv[4];
#pragma unroll
  for (int r = 0; r < 4; ++r) inv[r] = 1.0f / lrow[r];
  __bf16* Op = ob + ((size_t)b * kT + bq * 64 + wave * 16) * kC + h * kHD;
#pragma unroll
  for (int jd = 0; jd < 4; ++jd)
#pragma unroll
    for (int r = 0; r < 4; ++r)
      Op[(hi * 4 + r) * kC + jd * 16 + lo] = (__bf16)(acc[jd][r] * inv[r]);
}

extern "C" void kernel_launch(void* const* d_in, const int* in_sizes, int n_in,
                              void* d_out, int out_size, void* d_ws, size_t ws_size,
                              hipStream_t stream) {
  const float* x      = (const float*)d_in[0];
  const float* W_attn = (const float*)d_in[1];
  const float* b_attn = (const float*)d_in[2];
  const float* W_proj = (const float*)d_in[3];
  const float* b_proj = (const float*)d_in[4];
  float* out = (float*)d_out;

  char* ws = (char*)d_ws;
  // byte offsets (o aliases xb: xb dead after QKV GEMM)
  __bf16* xb  = (__bf16*)(ws + 0);          // 16,777,216 B  [8192,1024]
  __bf16* ob  = (__bf16*)(ws + 0);          // alias
  __bf16* wab = (__bf16*)(ws + 16777216);   //  6,291,456 B  [3072,1024]
  __bf16* wpb = (__bf16*)(ws + 23068672);   //  2,097,152 B  [1024,1024]
  __bf16* qbf = (__bf16*)(ws + 25165824);   // 16,777,216 B  [B,H,T,hd]
  __bf16* kbf = (__bf16*)(ws + 41943040);   // 16,777,216 B  [B,H,T,hd]
  __bf16* vtb = (__bf16*)(ws + 58720256);   // 16,777,216 B  [B,H,hd,T]

  k_convert_x<<<8192, 256, 0, stream>>>(x, xb);
  k_transpose_w<<<dim3(32, 96), 256, 0, stream>>>(W_attn, wab, 3072);
  k_transpose_w<<<dim3(32, 32), 256, 0, stream>>>(W_proj, wpb, 1024);
  k_gemm<0><<<dim3(24, 64), 256, 0, stream>>>(xb, wab, b_attn, qbf, kbf, vtb, nullptr);
  k_flash<<<dim3(32, 64), 256, 0, stream>>>(qbf, kbf, vtb, ob);
  k_gemm<1><<<dim3(8, 64), 256, 0, stream>>>(ob, wpb, b_proj, nullptr, nullptr, nullptr, out);
}